// Round 12
// baseline (836.630 us; speedup 1.0000x reference)
//
#include <hip/hip_runtime.h>
#include <float.h>

#define NB 64
#define NP 1024
#define KNN 10
#define SCAP 30   // survivors per (point, j-chunk)

__device__ __forceinline__ float lrelu(float v){ return v >= 0.0f ? v : 0.01f*v; }

// sorted-ascending bubble insert; strict < keeps earlier-inserted (lower j) on ties.
// Only static data flow (no runtime-indexed register arrays — R6 spill lesson).
#define TOP10_INSERT(dk_, ik_, bd_, bi_)              \
  { float dk=dk_; int ik=ik_;                         \
    _Pragma("unroll")                                 \
    for (int s=0;s<KNN;++s){                          \
      bool sw = dk < bd_[s];                          \
      float td=bd_[s]; int ti=bi_[s];                 \
      bd_[s]=sw?dk:td; bi_[s]=sw?ik:ti;               \
      dk=sw?td:dk;     ik=sw?ti:ik; } }

// ---------------- fused prep: build xx, wcomb, zero fmean, pa/pb for edgeconv1 ----------------
__global__ void prep_fused(const float* __restrict__ x, const float* __restrict__ pos,
                           const float* __restrict__ w2,
                           const float* __restrict__ w1a, const float* __restrict__ b1a,
                           float* __restrict__ xx, float* __restrict__ wcomb,
                           float* __restrict__ fmean,
                           float* __restrict__ pa, float* __restrict__ pb){
  int tid = blockIdx.x*256 + threadIdx.x;   // grid 4464 -> 1142784 threads
  if (tid < 65536){
    float4 v;
    v.x = x[tid];
    v.y = pos[3*tid+0];
    v.z = pos[3*tid+1];
    v.w = pos[3*tid+2];
    ((float4*)xx)[tid] = v;
  } else if (tid < 65536+16384){
    int i = tid - 65536;
    int op = i >> 6, c = i & 63;
    if (op < 128){
      wcomb[i] = w2[(64+c)*128 + op];
    } else {
      int o = op - 128;
      wcomb[i] = w2[c*128 + o] - w2[(64+c)*128 + o];
    }
  } else if (tid < 65536+16384+12288){
    int i = tid - 65536 - 16384;
    fmean[i] = 0.0f;
  } else {
    int i = tid - 94208;          // 0 .. 1048575 : (point, 4-output group)
    int n  = i >> 4;
    int o4 = i & 15;
    float x0 = x[n];
    float p0 = pos[3*n+0];
    float p1 = pos[3*n+1];
    float p2 = pos[3*n+2];
    float4 pav = *(const float4*)&b1a[o4*4];
    float4 pbv; pbv.x=0.0f; pbv.y=0.0f; pbv.z=0.0f; pbv.w=0.0f;
#define PREP_STEP(c_, xc_)                                          \
    { float4 wt = *(const float4*)&w1a[(c_)*64 + o4*4];             \
      float4 wb = *(const float4*)&w1a[((c_)+4)*64 + o4*4];         \
      pav.x = fmaf(xc_, wt.x - wb.x, pav.x);                        \
      pav.y = fmaf(xc_, wt.y - wb.y, pav.y);                        \
      pav.z = fmaf(xc_, wt.z - wb.z, pav.z);                        \
      pav.w = fmaf(xc_, wt.w - wb.w, pav.w);                        \
      pbv.x = fmaf(xc_, wb.x, pbv.x);                               \
      pbv.y = fmaf(xc_, wb.y, pbv.y);                               \
      pbv.z = fmaf(xc_, wb.z, pbv.z);                               \
      pbv.w = fmaf(xc_, wb.w, pbv.w); }
    PREP_STEP(0, x0)
    PREP_STEP(1, p0)
    PREP_STEP(2, p1)
    PREP_STEP(3, p2)
#undef PREP_STEP
    *(float4*)&pa[(size_t)n*64 + o4*4] = pav;
    *(float4*)&pb[(size_t)n*64 + o4*4] = pbv;
  }
}

// ---------------- knn1: 4-dim features, 4 i-quarters x 4 j-quarters ----------------
__global__ __launch_bounds__(256,2) void knn1_kernel(const float* __restrict__ xx,
                                                     float* __restrict__ bdh1,
                                                     int* __restrict__ bih1){
  __shared__ alignas(16) float sf[256*4];   // 4 KB j-quarter points
  __shared__ float ssq[256];
  int bid = blockIdx.x;        // 1024 = 64 b x 4 iq x 4 jq
  int b  = bid >> 4;
  int iq = (bid >> 2) & 3;
  int jq = bid & 3;
  int t = threadIdx.x;
  {
    float4 v = ((const float4*)xx)[(size_t)b*NP + jq*256 + t];
    ((float4*)sf)[t] = v;
    ssq[t] = ((v.x*v.x + v.y*v.y) + v.z*v.z) + v.w*v.w;
  }
  __syncthreads();
  int il = iq*256 + t;
  int n = b*NP + il;
  float4 fi = ((const float4*)xx)[n];
  float sqi = ((fi.x*fi.x + fi.y*fi.y) + fi.z*fi.z) + fi.w*fi.w;
  float bd[KNN]; int bi[KNN];
  #pragma unroll
  for (int s=0;s<KNN;++s){ bd[s]=FLT_MAX; bi[s]=0; }
  #pragma unroll 1
  for (int j=0;j<256;++j){
    float4 fj = ((float4*)sf)[j];
    float dot = fi.x*fj.x + fi.y*fj.y + fi.z*fj.z + fi.w*fj.w;
    float d2 = (sqi + ssq[j]) - 2.0f*dot;
    if (d2 < bd[KNN-1]){
      TOP10_INSERT(d2, jq*256+j, bd, bi);
    }
  }
  #pragma unroll
  for (int s=0;s<KNN;++s){
    bdh1[((size_t)n*4 + jq)*KNN + s] = bd[s];
    bih1[((size_t)n*4 + jq)*KNN + s] = bi[s];
  }
}

// ---------------- edgeconv1: 512 thr; wave w = output octile, lane = point ----------------
// (R4-measured best form: ~146 us, LDS 37888, occ 50%.) Weight addresses wave-uniform ->
// scalar loads from global; h rows in padded LDS; merge4 in prolog; padded-stage epilogue.
__global__ __launch_bounds__(512,4) void edgeconv1_kernel(
    const float* __restrict__ pa, const float* __restrict__ pb,
    const float* __restrict__ bdh1, const int* __restrict__ bih1,
    const float* __restrict__ w1b, const float* __restrict__ b1b,
    const float* __restrict__ w1c, const float* __restrict__ b1c,
    float* __restrict__ x1, float* __restrict__ sq2, float* __restrict__ fmean){
  __shared__ float hx0[64*65];               // 16.6 KB edge-0 h rows (+1 pad: bank spread)
  __shared__ float hx1[64*65];               // 16.6 KB edge-1 h rows
  __shared__ int   sidx[64*KNN];             // 2.5 KB merged idx1 for block's points
  __shared__ float ssq8[64*8];               // 2 KB per-wave partial squares
  int t = threadIdx.x;
  int b  = blockIdx.x >> 4;  // batch
  int g  = blockIdx.x & 15;  // point group

  // ---- fused merge4: thread t<64 merges point (b, g*64+t)'s 4 sorted lists
  if (t < 64){
    int nm = b*NP + g*64 + t;
    float A[KNN]; int Ai[KNN];
    #pragma unroll
    for (int s=0;s<KNN;++s){
      A[s]  = bdh1[(size_t)nm*4*KNN + s];
      Ai[s] = bih1[(size_t)nm*4*KNN + s];
    }
    #pragma unroll
    for (int q2i=1;q2i<4;++q2i){
      float T[KNN]; int Ti[KNN];
      #pragma unroll
      for (int s=0;s<KNN;++s){
        T[s]  = bdh1[((size_t)nm*4+q2i)*KNN + s];
        Ti[s] = bih1[((size_t)nm*4+q2i)*KNN + s];
      }
      float O[KNN]; int Oi[KNN];
      #pragma unroll
      for (int s=0;s<KNN;++s){
        bool ta = A[0] <= T[0];
        O[s]  = ta ? A[0]  : T[0];
        Oi[s] = ta ? Ai[0] : Ti[0];
        #pragma unroll
        for (int u=0;u<KNN-1;++u){
          A[u]  = ta ? A[u+1]  : A[u];
          Ai[u] = ta ? Ai[u+1] : Ai[u];
          T[u]  = ta ? T[u]    : T[u+1];
          Ti[u] = ta ? Ti[u]   : Ti[u+1];
        }
      }
      #pragma unroll
      for (int s=0;s<KNN;++s){ A[s]=O[s]; Ai[s]=Oi[s]; }
    }
    #pragma unroll
    for (int s=0;s<KNN;++s) sidx[t*KNN+s] = Ai[s];
  }
  __syncthreads();

  int wv = __builtin_amdgcn_readfirstlane(t >> 6);  // wave id = octile (forced uniform)
  int p  = t & 63;           // local point 0..63 (one per lane)
  int cb = wv*8;
  int n  = b*NP + g*64 + p;
  float* h0row = &hx0[p*65];
  float* h1row = &hx1[p*65];
  const float* wbq = w1b + cb;   // wave-uniform base -> s_load path
  const float* wcq = w1c + cb;

  float sbb[8], sbc[8];          // uniform -> SGPRs
  #pragma unroll
  for (int o=0;o<8;++o){ sbb[o]=b1b[cb+o]; sbc[o]=b1c[cb+o]; }

  float par[8];
  {
    float4 v0 = *(const float4*)&pa[(size_t)n*64 + cb];
    float4 v1 = *(const float4*)&pa[(size_t)n*64 + cb + 4];
    par[0]=v0.x; par[1]=v0.y; par[2]=v0.z; par[3]=v0.w;
    par[4]=v1.x; par[5]=v1.y; par[6]=v1.z; par[7]=v1.w;
  }
  float acc[8];
  #pragma unroll
  for (int o=0;o<8;++o) acc[o]=0.0f;

  #pragma unroll 1
  for (int kp=0; kp<5; ++kp){
    int j0 = sidx[p*KNN + kp*2];
    int j1 = sidx[p*KNN + kp*2 + 1];
    float4 u00 = *(const float4*)&pb[((size_t)b*NP + j0)*64 + cb];
    float4 u01 = *(const float4*)&pb[((size_t)b*NP + j0)*64 + cb + 4];
    float4 u10 = *(const float4*)&pb[((size_t)b*NP + j1)*64 + cb];
    float4 u11 = *(const float4*)&pb[((size_t)b*NP + j1)*64 + cb + 4];

    // ---- layer a (factored): h1 = lrelu(pa_i + pb_j)
    h0row[cb+0]=lrelu(par[0]+u00.x); h0row[cb+1]=lrelu(par[1]+u00.y);
    h0row[cb+2]=lrelu(par[2]+u00.z); h0row[cb+3]=lrelu(par[3]+u00.w);
    h0row[cb+4]=lrelu(par[4]+u01.x); h0row[cb+5]=lrelu(par[5]+u01.y);
    h0row[cb+6]=lrelu(par[6]+u01.z); h0row[cb+7]=lrelu(par[7]+u01.w);
    h1row[cb+0]=lrelu(par[0]+u10.x); h1row[cb+1]=lrelu(par[1]+u10.y);
    h1row[cb+2]=lrelu(par[2]+u10.z); h1row[cb+3]=lrelu(par[3]+u10.w);
    h1row[cb+4]=lrelu(par[4]+u11.x); h1row[cb+5]=lrelu(par[5]+u11.y);
    h1row[cb+6]=lrelu(par[6]+u11.z); h1row[cb+7]=lrelu(par[7]+u11.w);
    __syncthreads();

    // ---- layer b: h from LDS (2-way aliased b32), weights scalar from global
    float pr0[8], pr1[8];
    #pragma unroll
    for (int o=0;o<8;++o){ pr0[o]=sbb[o]; pr1[o]=sbb[o]; }
    #pragma unroll 4
    for (int c=0;c<64;++c){
      float hv0 = h0row[c];
      float hv1 = h1row[c];
      float4 w0 = *(const float4*)&wbq[c*64];
      float4 w1 = *(const float4*)&wbq[c*64+4];
      pr0[0]=fmaf(hv0,w0.x,pr0[0]); pr0[1]=fmaf(hv0,w0.y,pr0[1]);
      pr0[2]=fmaf(hv0,w0.z,pr0[2]); pr0[3]=fmaf(hv0,w0.w,pr0[3]);
      pr0[4]=fmaf(hv0,w1.x,pr0[4]); pr0[5]=fmaf(hv0,w1.y,pr0[5]);
      pr0[6]=fmaf(hv0,w1.z,pr0[6]); pr0[7]=fmaf(hv0,w1.w,pr0[7]);
      pr1[0]=fmaf(hv1,w0.x,pr1[0]); pr1[1]=fmaf(hv1,w0.y,pr1[1]);
      pr1[2]=fmaf(hv1,w0.z,pr1[2]); pr1[3]=fmaf(hv1,w0.w,pr1[3]);
      pr1[4]=fmaf(hv1,w1.x,pr1[4]); pr1[5]=fmaf(hv1,w1.y,pr1[5]);
      pr1[6]=fmaf(hv1,w1.z,pr1[6]); pr1[7]=fmaf(hv1,w1.w,pr1[7]);
    }
    __syncthreads();              // all h reads done before overwrite
    #pragma unroll
    for (int o=0;o<8;++o){ h0row[cb+o]=lrelu(pr0[o]); h1row[cb+o]=lrelu(pr1[o]); }
    __syncthreads();

    // ---- layer c: accumulate my 8 outputs, both edges
    #pragma unroll
    for (int o=0;o<8;++o){ pr0[o]=sbc[o]; pr1[o]=sbc[o]; }
    #pragma unroll 4
    for (int c=0;c<64;++c){
      float hv0 = h0row[c];
      float hv1 = h1row[c];
      float4 w0 = *(const float4*)&wcq[c*64];
      float4 w1 = *(const float4*)&wcq[c*64+4];
      pr0[0]=fmaf(hv0,w0.x,pr0[0]); pr0[1]=fmaf(hv0,w0.y,pr0[1]);
      pr0[2]=fmaf(hv0,w0.z,pr0[2]); pr0[3]=fmaf(hv0,w0.w,pr0[3]);
      pr0[4]=fmaf(hv0,w1.x,pr0[4]); pr0[5]=fmaf(hv0,w1.y,pr0[5]);
      pr0[6]=fmaf(hv0,w1.z,pr0[6]); pr0[7]=fmaf(hv0,w1.w,pr0[7]);
      pr1[0]=fmaf(hv1,w0.x,pr1[0]); pr1[1]=fmaf(hv1,w0.y,pr1[1]);
      pr1[2]=fmaf(hv1,w0.z,pr1[2]); pr1[3]=fmaf(hv1,w0.w,pr1[3]);
      pr1[4]=fmaf(hv1,w1.x,pr1[4]); pr1[5]=fmaf(hv1,w1.y,pr1[5]);
      pr1[6]=fmaf(hv1,w1.z,pr1[6]); pr1[7]=fmaf(hv1,w1.w,pr1[7]);
    }
    #pragma unroll
    for (int o=0;o<8;++o) acc[o] += lrelu(pr0[o]) + lrelu(pr1[o]);
    __syncthreads();              // rows free for next pair
  }

  // ---- epilogue: per-thread squares, stage acc into hx0
  {
    float s = 0.0f;
    #pragma unroll
    for (int o=0;o<8;++o) s = fmaf(acc[o], acc[o], s);
    ssq8[p*8 + wv] = s;
  }
  #pragma unroll
  for (int o=0;o<8;++o) h0row[cb+o] = acc[o];
  __syncthreads();

  // coalesced x1 write from staged hx0
  for (int i=t; i<1024; i+=512){
    int p2 = i >> 4;
    int c4 = (i & 15) << 2;
    float4 v;
    v.x = hx0[p2*65 + c4];
    v.y = hx0[p2*65 + c4 + 1];
    v.z = hx0[p2*65 + c4 + 2];
    v.w = hx0[p2*65 + c4 + 3];
    *(float4*)&x1[((size_t)(b*NP + g*64 + p2))*64 + c4] = v;
  }

  // fused x1-mean partial + sq2
  if (t < 64){
    float s2 = 0.0f;
    #pragma unroll 8
    for (int p2=0;p2<64;++p2) s2 += hx0[p2*65 + t];
    atomicAdd(&fmean[b*192 + t], s2);
    float ss = 0.0f;
    #pragma unroll
    for (int w=0;w<8;++w) ss += ssq8[t*8 + w];
    sq2[b*NP + g*64 + t] = ss;
  }
}

// ---------------- knn2 phase A: top-10 per (i-point, j-quarter of [0,256)) ----------------
// Grid 1024 -> 4 blocks/CU, 16 waves/CU (R10-proven). Exact per-quarter lists; merge in
// knn2_mergeT reproduces the identical seed list + threshold.
__global__ __launch_bounds__(256,4) void knn2_thresh_q(const float* __restrict__ x1,
    const float* __restrict__ sq2,
    float* __restrict__ bdh2, int* __restrict__ bih2){
  __shared__ alignas(16) float sj[64*64];    // 16 KB: 64 j-rows
  __shared__ float ssq[64];
  int bid = blockIdx.x;        // 1024 = 64 b x 4 ig x 4 jq
  int b  = bid >> 4;
  int ig = (bid >> 2) & 3;
  int jq = bid & 3;
  int t = threadIdx.x;
  {
    const float4* src = (const float4*)(x1 + ((size_t)b*NP + jq*64)*64);
    for (int u=t; u<1024; u+=256) ((float4*)sj)[u] = src[u];
    if (t < 64) ssq[t] = sq2[b*NP + jq*64 + t];
  }
  int n = b*NP + ig*256 + t;
  float xi[64];
  #pragma unroll
  for (int c=0;c<64;c+=4){
    float4 v = *(const float4*)&x1[(size_t)n*64+c];
    xi[c]=v.x; xi[c+1]=v.y; xi[c+2]=v.z; xi[c+3]=v.w;
  }
  float sqi = sq2[n];
  float bd[KNN]; int bi[KNN];
  #pragma unroll
  for (int s=0;s<KNN;++s){ bd[s]=FLT_MAX; bi[s]=0; }
  __syncthreads();
  #pragma unroll 2
  for (int j=0;j<64;++j){
    float d0=0.f, d1=0.f, d2a=0.f, d3=0.f;   // 4-way chain split
    #pragma unroll
    for (int c=0;c<64;c+=16){
      float4 v0 = *(const float4*)&sj[j*64+c];
      float4 v1 = *(const float4*)&sj[j*64+c+4];
      float4 v2 = *(const float4*)&sj[j*64+c+8];
      float4 v3 = *(const float4*)&sj[j*64+c+12];
      d0=fmaf(xi[c+0],v0.x,d0);  d0=fmaf(xi[c+1],v0.y,d0);
      d0=fmaf(xi[c+2],v0.z,d0);  d0=fmaf(xi[c+3],v0.w,d0);
      d1=fmaf(xi[c+4],v1.x,d1);  d1=fmaf(xi[c+5],v1.y,d1);
      d1=fmaf(xi[c+6],v1.z,d1);  d1=fmaf(xi[c+7],v1.w,d1);
      d2a=fmaf(xi[c+8],v2.x,d2a);  d2a=fmaf(xi[c+9],v2.y,d2a);
      d2a=fmaf(xi[c+10],v2.z,d2a); d2a=fmaf(xi[c+11],v2.w,d2a);
      d3=fmaf(xi[c+12],v3.x,d3);  d3=fmaf(xi[c+13],v3.y,d3);
      d3=fmaf(xi[c+14],v3.z,d3);  d3=fmaf(xi[c+15],v3.w,d3);
    }
    float dot = (d0+d1)+(d2a+d3);
    float d2 = (sqi + ssq[j]) - 2.0f*dot;
    if (d2 < bd[KNN-1]){
      TOP10_INSERT(d2, jq*64+j, bd, bi);
    }
  }
  #pragma unroll
  for (int s=0;s<KNN;++s){
    bdh2[((size_t)n*4 + jq)*KNN + s] = bd[s];
    bih2[((size_t)n*4 + jq)*KNN + s] = bi[s];
  }
}

// ---------------- knn2 mergeT: fuse 4 quarter-lists -> seed list + threshold ----------------
__global__ __launch_bounds__(256) void knn2_mergeT(const float* __restrict__ bdh2,
    const int* __restrict__ bih2,
    float* __restrict__ seed_d, int* __restrict__ seed_i, float* __restrict__ Tout){
  int nm = blockIdx.x*256 + threadIdx.x;
  float A[KNN]; int Ai[KNN];
  #pragma unroll
  for (int s=0;s<KNN;++s){
    A[s]  = bdh2[(size_t)nm*4*KNN + s];
    Ai[s] = bih2[(size_t)nm*4*KNN + s];
  }
  #pragma unroll
  for (int q2i=1;q2i<4;++q2i){
    float T[KNN]; int Ti[KNN];
    #pragma unroll
    for (int s=0;s<KNN;++s){
      T[s]  = bdh2[((size_t)nm*4+q2i)*KNN + s];
      Ti[s] = bih2[((size_t)nm*4+q2i)*KNN + s];
    }
    float O[KNN]; int Oi[KNN];
    #pragma unroll
    for (int s=0;s<KNN;++s){
      bool ta = A[0] <= T[0];
      O[s]  = ta ? A[0]  : T[0];
      Oi[s] = ta ? Ai[0] : Ti[0];
      #pragma unroll
      for (int u=0;u<KNN-1;++u){
        A[u]  = ta ? A[u+1]  : A[u];
        Ai[u] = ta ? Ai[u+1] : Ai[u];
        T[u]  = ta ? T[u]    : T[u+1];
        Ti[u] = ta ? Ti[u]   : Ti[u+1];
      }
    }
    #pragma unroll
    for (int s=0;s<KNN;++s){ A[s]=O[s]; Ai[s]=Oi[s]; }
  }
  #pragma unroll
  for (int s=0;s<KNN;++s){
    seed_d[(size_t)nm*KNN + s] = A[s];
    seed_i[(size_t)nm*KNN + s] = Ai[s];
  }
  Tout[nm] = A[KNN-1];
}

// ---------------- knn2 phase B: filtered scan of j in [256,1024), 4 chunks ----------------
// R12: 3 tiles x 64 rows (16 KB LDS) + launch_bounds(256,4) -> 4 blocks/CU, 16 waves/CU
// (R10 thresh lesson: LDS-broadcast loops need >=16 waves/CU to hide the broadcast
// return path under VALU). Survivor order (ascending j within chunk) unchanged.
__global__ __launch_bounds__(256,4) void knn2_scan(const float* __restrict__ x1,
    const float* __restrict__ sq2, const float* __restrict__ Tin,
    float2* __restrict__ surv, int* __restrict__ cnt4){
  __shared__ alignas(16) float sj[64*64];    // 16 KB
  __shared__ float ssq[64];
  int bid = blockIdx.x;     // 1024 = 64 b x 4 ig x 4 jc
  int b  = bid >> 4;
  int ig = (bid >> 2) & 3;
  int jc = bid & 3;
  int t = threadIdx.x;
  int n = b*NP + ig*256 + t;
  float xi[64];
  #pragma unroll
  for (int c=0;c<64;c+=4){
    float4 v = *(const float4*)&x1[(size_t)n*64+c];
    xi[c]=v.x; xi[c+1]=v.y; xi[c+2]=v.z; xi[c+3]=v.w;
  }
  float sqi = sq2[n];
  float thr = Tin[n];
  int cnt = 0;
  float2* mybuf = surv + ((size_t)n*4 + jc)*SCAP;
  int jbase0 = 256 + jc*192;
  for (int tile=0; tile<3; ++tile){
    int jb = jbase0 + tile*64;
    __syncthreads();
    const float4* src = (const float4*)(x1 + ((size_t)b*NP + jb)*64);
    for (int u=t; u<1024; u+=256) ((float4*)sj)[u] = src[u];
    if (t < 64) ssq[t] = sq2[b*NP + jb + t];
    __syncthreads();
    #pragma unroll 2
    for (int j=0;j<64;++j){
      float a0=0.f, a1=0.f;                  // 2-way chain split
      #pragma unroll
      for (int c=0;c<64;c+=8){
        float4 v0 = *(const float4*)&sj[j*64+c];
        float4 v1 = *(const float4*)&sj[j*64+c+4];
        a0=fmaf(xi[c+0],v0.x,a0); a0=fmaf(xi[c+1],v0.y,a0);
        a0=fmaf(xi[c+2],v0.z,a0); a0=fmaf(xi[c+3],v0.w,a0);
        a1=fmaf(xi[c+4],v1.x,a1); a1=fmaf(xi[c+5],v1.y,a1);
        a1=fmaf(xi[c+6],v1.z,a1); a1=fmaf(xi[c+7],v1.w,a1);
      }
      float d2 = (sqi + ssq[j]) - 2.0f*(a0+a1);
      if (d2 <= thr && cnt < SCAP){
        float2 e; e.x = d2; e.y = __int_as_float(jb + j);
        mybuf[cnt] = e;
        cnt++;
      }
    }
  }
  cnt4[(size_t)n*4 + jc] = cnt;
}

// ---------------- knn2 phase C: replay survivors into seed list ----------------
__global__ void knn2_select(const float* __restrict__ seed_d, const int* __restrict__ seed_i,
    const float2* __restrict__ surv, const int* __restrict__ cnt4,
    int* __restrict__ idx2){
  int n = blockIdx.x*256 + threadIdx.x;
  float bd[KNN]; int bi[KNN];
  #pragma unroll
  for (int s=0;s<KNN;++s){
    bd[s] = seed_d[(size_t)n*KNN + s];
    bi[s] = seed_i[(size_t)n*KNN + s];
  }
  #pragma unroll 1
  for (int c=0;c<4;++c){
    int nc = cnt4[(size_t)n*4 + c];
    const float2* buf = surv + ((size_t)n*4 + c)*SCAP;
    #pragma unroll 1
    for (int k=0;k<nc;++k){
      float2 e = buf[k];
      float d = e.x; int j = __float_as_int(e.y);
      if (d < bd[KNN-1]){
        TOP10_INSERT(d, j, bd, bi);
      }
    }
  }
  #pragma unroll
  for (int s=0;s<KNN;++s) idx2[(size_t)n*KNN+s] = bi[s];
}

// ---------------- q/r GEMM for edgeconv2: q=x1*Wbot, r=x1*(Wtop-Wbot)+b ----------------
// 4-way op-split: grid 1024, 4 blocks/CU, 16 waves/CU. (R5 proven form.)
__global__ __launch_bounds__(256) void qr2_kernel(const float* __restrict__ x1,
    const float* __restrict__ wcombg, const float* __restrict__ b2,
    float* __restrict__ q2, float* __restrict__ r2){
  __shared__ alignas(16) float sw[4096];     // 16 KB: rows 0..31 = a(oq+r), 32..63 = c(128+oq+r)
  __shared__ float sb2l[32];
  int t = threadIdx.x;
  int oq = (blockIdx.x & 3) * 32;
  int n  = (blockIdx.x >> 2) * 256 + t;
  for (int u=t; u<1024; u+=256){
    int row = u >> 4;
    int c4  = u & 15;
    int src = (row < 32) ? (oq + row) : (96 + oq + row);
    ((float4*)sw)[u] = ((const float4*)wcombg)[src*16 + c4];
  }
  if (t < 32) sb2l[t] = b2[oq + t];
  __syncthreads();
  float xi[64];
  #pragma unroll
  for (int c=0;c<64;c+=4){
    float4 v = *(const float4*)&x1[(size_t)n*64+c];
    xi[c]=v.x; xi[c+1]=v.y; xi[c+2]=v.z; xi[c+3]=v.w;
  }
  #pragma unroll 1
  for (int op=0; op<32; op+=4){
    float q0=0,q1=0,q2a=0,q3=0, r0,r1,r2a,r3;
    r0=sb2l[op]; r1=sb2l[op+1]; r2a=sb2l[op+2]; r3=sb2l[op+3];
    #pragma unroll
    for (int c=0;c<64;c+=4){
      float4 a0 = *(const float4*)&sw[(op+0)*64+c];
      float4 a1 = *(const float4*)&sw[(op+1)*64+c];
      float4 a2 = *(const float4*)&sw[(op+2)*64+c];
      float4 a3 = *(const float4*)&sw[(op+3)*64+c];
      float4 c0 = *(const float4*)&sw[(32+op+0)*64+c];
      float4 c1 = *(const float4*)&sw[(32+op+1)*64+c];
      float4 c2 = *(const float4*)&sw[(32+op+2)*64+c];
      float4 c3 = *(const float4*)&sw[(32+op+3)*64+c];
      q0=fmaf(xi[c],a0.x,q0); q0=fmaf(xi[c+1],a0.y,q0); q0=fmaf(xi[c+2],a0.z,q0); q0=fmaf(xi[c+3],a0.w,q0);
      q1=fmaf(xi[c],a1.x,q1); q1=fmaf(xi[c+1],a1.y,q1); q1=fmaf(xi[c+2],a1.z,q1); q1=fmaf(xi[c+3],a1.w,q1);
      q2a=fmaf(xi[c],a2.x,q2a); q2a=fmaf(xi[c+1],a2.y,q2a); q2a=fmaf(xi[c+2],a2.z,q2a); q2a=fmaf(xi[c+3],a2.w,q2a);
      q3=fmaf(xi[c],a3.x,q3); q3=fmaf(xi[c+1],a3.y,q3); q3=fmaf(xi[c+2],a3.z,q3); q3=fmaf(xi[c+3],a3.w,q3);
      r0=fmaf(xi[c],c0.x,r0); r0=fmaf(xi[c+1],c0.y,r0); r0=fmaf(xi[c+2],c0.z,r0); r0=fmaf(xi[c+3],c0.w,r0);
      r1=fmaf(xi[c],c1.x,r1); r1=fmaf(xi[c+1],c1.y,r1); r1=fmaf(xi[c+2],c1.z,r1); r1=fmaf(xi[c+3],c1.w,r1);
      r2a=fmaf(xi[c],c2.x,r2a); r2a=fmaf(xi[c+1],c2.y,r2a); r2a=fmaf(xi[c+2],c2.z,r2a); r2a=fmaf(xi[c+3],c2.w,r2a);
      r3=fmaf(xi[c],c3.x,r3); r3=fmaf(xi[c+1],c3.y,r3); r3=fmaf(xi[c+2],c3.z,r3); r3=fmaf(xi[c+3],c3.w,r3);
    }
    float4 qv; qv.x=q0; qv.y=q1; qv.z=q2a; qv.w=q3;
    float4 rv; rv.x=r0; rv.y=r1; rv.z=r2a; rv.w=r3;
    *(float4*)&q2[(size_t)n*128+oq+op] = qv;
    *(float4*)&r2[(size_t)n*128+oq+op] = rv;
  }
}

// ---------------- edgeconv2 gather + fused mean (never materialize x2) ----------------
// k-loop fully unrolled: 10 idx2 loads issued first, then 10 independent q2 row loads
// (MLP ~10 in flight vs 1 with the serialized loop); accumulation stays in k order.
__global__ __launch_bounds__(256,4) void ec2_gather_kernel(
    const float* __restrict__ q2, const float* __restrict__ r2,
    const int* __restrict__ idx2, float* __restrict__ fmean){
  __shared__ alignas(16) float4 red[256];
  int t = threadIdx.x;
  int b = blockIdx.x >> 7, blk = blockIdx.x & 127;
  int p = t >> 5, c4 = t & 31;
  int n = b*NP + blk*8 + p;
  float4 r = *(const float4*)&r2[(size_t)n*128 + c4*4];
  int jA[KNN];
  #pragma unroll
  for (int k=0;k<KNN;++k) jA[k] = idx2[n*KNN+k];
  float4 qv[KNN];
  #pragma unroll
  for (int k=0;k<KNN;++k)
    qv[k] = *(const float4*)&q2[((size_t)b*NP + jA[k])*128 + c4*4];
  float4 acc; acc.x=0; acc.y=0; acc.z=0; acc.w=0;
  #pragma unroll
  for (int k=0;k<KNN;++k){
    acc.x += lrelu(r.x+qv[k].x);
    acc.y += lrelu(r.y+qv[k].y);
    acc.z += lrelu(r.z+qv[k].z);
    acc.w += lrelu(r.w+qv[k].w);
  }
  red[t] = acc;
  __syncthreads();
  if (t < 128){ float4 o = red[t+128]; red[t].x+=o.x; red[t].y+=o.y; red[t].z+=o.z; red[t].w+=o.w; }
  __syncthreads();
  if (t < 64){ float4 o = red[t+64]; red[t].x+=o.x; red[t].y+=o.y; red[t].z+=o.z; red[t].w+=o.w; }
  __syncthreads();
  if (t < 32){
    float4 s = red[t]; float4 o = red[t+32];
    s.x+=o.x; s.y+=o.y; s.z+=o.z; s.w+=o.w;
    float* dst = &fmean[b*192 + 64 + c4*4];
    atomicAdd(dst+0, s.x); atomicAdd(dst+1, s.y);
    atomicAdd(dst+2, s.z); atomicAdd(dst+3, s.w);
  }
}

// ---------------- head, split for parallelism ----------------
__global__ __launch_bounds__(256) void headA_kernel(const float* __restrict__ fmean,
    const float* __restrict__ wl, const float* __restrict__ bl,
    float* __restrict__ o1g){
  __shared__ float v0[192];
  int b = blockIdx.x >> 2, ch = blockIdx.x & 3, t = threadIdx.x;
  if (t < 192) v0[t] = fmean[b*192 + t] * (1.0f/1024.0f);
  __syncthreads();
  int o = ch*256 + t;
  float s = bl[o];
  #pragma unroll 8
  for (int c=0;c<192;++c) s = fmaf(v0[c], wl[c*1024 + o], s);
  o1g[b*1024 + o] = s;
}

__global__ __launch_bounds__(256) void headB_kernel(const float* __restrict__ o1g,
    const float* __restrict__ wm1, const float* __restrict__ bm1,
    float* __restrict__ h1g){
  __shared__ alignas(16) float vo[1024];
  int b = blockIdx.x >> 1, ch = blockIdx.x & 1, t = threadIdx.x;
  ((float4*)vo)[t] = ((const float4*)(o1g + b*1024))[t];
  __syncthreads();
  int o = ch*256 + t;
  float s = bm1[o];
  #pragma unroll 8
  for (int c=0;c<1024;++c) s = fmaf(vo[c], wm1[c*512 + o], s);
  h1g[b*512 + o] = lrelu(s);
}

__global__ __launch_bounds__(256) void headC_kernel(const float* __restrict__ h1g,
    const float* __restrict__ wm2, const float* __restrict__ bm2,
    const float* __restrict__ wm3, const float* __restrict__ bm3,
    float* __restrict__ out){
  __shared__ alignas(16) float vh[512];
  __shared__ float h2[256];
  int b = blockIdx.x, t = threadIdx.x;
  ((float2*)vh)[t] = ((const float2*)(h1g + b*512))[t];
  __syncthreads();
  float s = bm2[t];
  #pragma unroll 8
  for (int c=0;c<512;++c) s = fmaf(vh[c], wm2[c*256 + t], s);
  h2[t] = lrelu(s);
  __syncthreads();
  if (t < 3){
    float s2 = bm3[t];
    #pragma unroll 8
    for (int c=0;c<256;++c) s2 = fmaf(h2[c], wm3[c*3 + t], s2);
    out[b*3 + t] = s2;
  }
}

extern "C" void kernel_launch(void* const* d_in, const int* in_sizes, int n_in,
                              void* d_out, int out_size, void* d_ws, size_t ws_size,
                              hipStream_t stream) {
  const float* x   = (const float*)d_in[0];
  const float* pos = (const float*)d_in[1];
  const float* w1a = (const float*)d_in[3];
  const float* b1a = (const float*)d_in[4];
  const float* w1b = (const float*)d_in[5];
  const float* b1b = (const float*)d_in[6];
  const float* w1c = (const float*)d_in[7];
  const float* b1c = (const float*)d_in[8];
  const float* w2  = (const float*)d_in[9];
  const float* b2  = (const float*)d_in[10];
  const float* wl  = (const float*)d_in[11];
  const float* bl  = (const float*)d_in[12];
  const float* wm1 = (const float*)d_in[13];
  const float* bm1 = (const float*)d_in[14];
  const float* wm2 = (const float*)d_in[15];
  const float* bm2 = (const float*)d_in[16];
  const float* wm3 = (const float*)d_in[17];
  const float* bm3 = (const float*)d_in[18];
  float* out = (float*)d_out;

  float* ws_f  = (float*)d_ws;
  float* xx    = ws_f;                    // 262144 f
  float* x1    = xx + 262144;             // 4194304 f (16 MB)
  float* sq2   = x1 + 4194304;            // 65536 f
  int*   idx2  = (int*)(sq2 + 65536);     // 655360 i
  float* q2    = (float*)(idx2 + 655360); // 8388608 f (32 MB)
  float* r2    = q2 + 8388608;            // 8388608 f (32 MB)
  float* wcomb = r2 + 8388608;            // 16384 f
  float* fmean = wcomb + 16384;           // 12288 f
  float* o1g   = fmean + 12288;           // 65536 f
  float* h1g   = o1g + 65536;             // 32768 f
  float* seedd = h1g + 32768;             // 655360 f
  int*   seedi = (int*)(seedd + 655360);  // 655360 i
  float* Tbuf  = (float*)(seedi + 655360);// 65536 f
  int*   cnt4  = (int*)(Tbuf + 65536);    // 262144 i
  // Temporal overlays:
  // r2 region: knn1 writes bdh1/bih1 -> ec1 merge reads -> knn2_thresh_q REUSES the
  //   region for bdh2/bih2 -> knn2_mergeT reads -> qr2 overwrites r2 (strictly later).
  float* bdh1  = r2;                      // 2621440 f
  int*   bih1  = (int*)(r2 + 2621440);    // 2621440 i
  float* bdh2  = bdh1;
  int*   bih2  = bih1;
  // q2 region: prep writes pa/pb -> ec1 consumes -> surv (scan) -> qr2 overwrites q2.
  float2* surv = (float2*)q2;             // knn2 survivors (written after ec1)
  float* pa    = q2;                      // 4194304 f (16 MB)
  float* pb    = q2 + 4194304;            // 4194304 f (16 MB)

  prep_fused<<<4464, 256, 0, stream>>>(x, pos, w2, w1a, b1a, xx, wcomb, fmean, pa, pb);
  knn1_kernel<<<1024, 256, 0, stream>>>(xx, bdh1, bih1);
  edgeconv1_kernel<<<1024, 512, 0, stream>>>(pa, pb, bdh1, bih1, w1b, b1b, w1c, b1c, x1, sq2, fmean);
  knn2_thresh_q<<<1024, 256, 0, stream>>>(x1, sq2, bdh2, bih2);
  knn2_mergeT<<<256, 256, 0, stream>>>(bdh2, bih2, seedd, seedi, Tbuf);
  knn2_scan<<<1024, 256, 0, stream>>>(x1, sq2, Tbuf, surv, cnt4);
  knn2_select<<<256, 256, 0, stream>>>(seedd, seedi, surv, cnt4, idx2);
  qr2_kernel<<<1024, 256, 0, stream>>>(x1, wcomb, b2, q2, r2);
  ec2_gather_kernel<<<8192, 256, 0, stream>>>(q2, r2, idx2, fmean);
  headA_kernel<<<256, 256, 0, stream>>>(fmean, wl, bl, o1g);
  headB_kernel<<<128, 256, 0, stream>>>(o1g, wm1, bm1, h1g);
  headC_kernel<<<64, 256, 0, stream>>>(h1g, wm2, bm2, wm3, bm3, out);
}

// Round 13
// 822.668 us; speedup vs baseline: 1.0170x; 1.0170x over previous
//
#include <hip/hip_runtime.h>
#include <float.h>

#define NB 64
#define NP 1024
#define KNN 10
#define SCAP 30   // survivors per (point, j-chunk)

__device__ __forceinline__ float lrelu(float v){ return v >= 0.0f ? v : 0.01f*v; }

// sorted-ascending bubble insert; strict < keeps earlier-inserted (lower j) on ties.
// Only static data flow (no runtime-indexed register arrays — R6 spill lesson).
#define TOP10_INSERT(dk_, ik_, bd_, bi_)              \
  { float dk=dk_; int ik=ik_;                         \
    _Pragma("unroll")                                 \
    for (int s=0;s<KNN;++s){                          \
      bool sw = dk < bd_[s];                          \
      float td=bd_[s]; int ti=bi_[s];                 \
      bd_[s]=sw?dk:td; bi_[s]=sw?ik:ti;               \
      dk=sw?td:dk;     ik=sw?ti:ik; } }

// ---------------- fused prep: build xx, wcomb, zero fmean, pa/pb for edgeconv1 ----------------
__global__ void prep_fused(const float* __restrict__ x, const float* __restrict__ pos,
                           const float* __restrict__ w2,
                           const float* __restrict__ w1a, const float* __restrict__ b1a,
                           float* __restrict__ xx, float* __restrict__ wcomb,
                           float* __restrict__ fmean,
                           float* __restrict__ pa, float* __restrict__ pb){
  int tid = blockIdx.x*256 + threadIdx.x;   // grid 4464 -> 1142784 threads
  if (tid < 65536){
    float4 v;
    v.x = x[tid];
    v.y = pos[3*tid+0];
    v.z = pos[3*tid+1];
    v.w = pos[3*tid+2];
    ((float4*)xx)[tid] = v;
  } else if (tid < 65536+16384){
    int i = tid - 65536;
    int op = i >> 6, c = i & 63;
    if (op < 128){
      wcomb[i] = w2[(64+c)*128 + op];
    } else {
      int o = op - 128;
      wcomb[i] = w2[c*128 + o] - w2[(64+c)*128 + o];
    }
  } else if (tid < 65536+16384+12288){
    int i = tid - 65536 - 16384;
    fmean[i] = 0.0f;
  } else {
    int i = tid - 94208;          // 0 .. 1048575 : (point, 4-output group)
    int n  = i >> 4;
    int o4 = i & 15;
    float x0 = x[n];
    float p0 = pos[3*n+0];
    float p1 = pos[3*n+1];
    float p2 = pos[3*n+2];
    float4 pav = *(const float4*)&b1a[o4*4];
    float4 pbv; pbv.x=0.0f; pbv.y=0.0f; pbv.z=0.0f; pbv.w=0.0f;
#define PREP_STEP(c_, xc_)                                          \
    { float4 wt = *(const float4*)&w1a[(c_)*64 + o4*4];             \
      float4 wb = *(const float4*)&w1a[((c_)+4)*64 + o4*4];         \
      pav.x = fmaf(xc_, wt.x - wb.x, pav.x);                        \
      pav.y = fmaf(xc_, wt.y - wb.y, pav.y);                        \
      pav.z = fmaf(xc_, wt.z - wb.z, pav.z);                        \
      pav.w = fmaf(xc_, wt.w - wb.w, pav.w);                        \
      pbv.x = fmaf(xc_, wb.x, pbv.x);                               \
      pbv.y = fmaf(xc_, wb.y, pbv.y);                               \
      pbv.z = fmaf(xc_, wb.z, pbv.z);                               \
      pbv.w = fmaf(xc_, wb.w, pbv.w); }
    PREP_STEP(0, x0)
    PREP_STEP(1, p0)
    PREP_STEP(2, p1)
    PREP_STEP(3, p2)
#undef PREP_STEP
    *(float4*)&pa[(size_t)n*64 + o4*4] = pav;
    *(float4*)&pb[(size_t)n*64 + o4*4] = pbv;
  }
}

// ---------------- knn1: 4-dim features, 4 i-quarters x 4 j-quarters ----------------
__global__ __launch_bounds__(256,2) void knn1_kernel(const float* __restrict__ xx,
                                                     float* __restrict__ bdh1,
                                                     int* __restrict__ bih1){
  __shared__ alignas(16) float sf[256*4];   // 4 KB j-quarter points
  __shared__ float ssq[256];
  int bid = blockIdx.x;        // 1024 = 64 b x 4 iq x 4 jq
  int b  = bid >> 4;
  int iq = (bid >> 2) & 3;
  int jq = bid & 3;
  int t = threadIdx.x;
  {
    float4 v = ((const float4*)xx)[(size_t)b*NP + jq*256 + t];
    ((float4*)sf)[t] = v;
    ssq[t] = ((v.x*v.x + v.y*v.y) + v.z*v.z) + v.w*v.w;
  }
  __syncthreads();
  int il = iq*256 + t;
  int n = b*NP + il;
  float4 fi = ((const float4*)xx)[n];
  float sqi = ((fi.x*fi.x + fi.y*fi.y) + fi.z*fi.z) + fi.w*fi.w;
  float bd[KNN]; int bi[KNN];
  #pragma unroll
  for (int s=0;s<KNN;++s){ bd[s]=FLT_MAX; bi[s]=0; }
  #pragma unroll 1
  for (int j=0;j<256;++j){
    float4 fj = ((float4*)sf)[j];
    float dot = fi.x*fj.x + fi.y*fj.y + fi.z*fj.z + fi.w*fj.w;
    float d2 = (sqi + ssq[j]) - 2.0f*dot;
    if (d2 < bd[KNN-1]){
      TOP10_INSERT(d2, jq*256+j, bd, bi);
    }
  }
  #pragma unroll
  for (int s=0;s<KNN;++s){
    bdh1[((size_t)n*4 + jq)*KNN + s] = bd[s];
    bih1[((size_t)n*4 + jq)*KNN + s] = bi[s];
  }
}

// ---------------- edgeconv1: 512 thr; wave w = output octile, lane = point ----------------
// (R4-measured best form: ~146 us, LDS 37888, occ 50%.) Weight addresses wave-uniform ->
// scalar loads from global; h rows in padded LDS; merge4 in prolog; padded-stage epilogue.
__global__ __launch_bounds__(512,4) void edgeconv1_kernel(
    const float* __restrict__ pa, const float* __restrict__ pb,
    const float* __restrict__ bdh1, const int* __restrict__ bih1,
    const float* __restrict__ w1b, const float* __restrict__ b1b,
    const float* __restrict__ w1c, const float* __restrict__ b1c,
    float* __restrict__ x1, float* __restrict__ sq2, float* __restrict__ fmean){
  __shared__ float hx0[64*65];               // 16.6 KB edge-0 h rows (+1 pad: bank spread)
  __shared__ float hx1[64*65];               // 16.6 KB edge-1 h rows
  __shared__ int   sidx[64*KNN];             // 2.5 KB merged idx1 for block's points
  __shared__ float ssq8[64*8];               // 2 KB per-wave partial squares
  int t = threadIdx.x;
  int b  = blockIdx.x >> 4;  // batch
  int g  = blockIdx.x & 15;  // point group

  // ---- fused merge4: thread t<64 merges point (b, g*64+t)'s 4 sorted lists
  if (t < 64){
    int nm = b*NP + g*64 + t;
    float A[KNN]; int Ai[KNN];
    #pragma unroll
    for (int s=0;s<KNN;++s){
      A[s]  = bdh1[(size_t)nm*4*KNN + s];
      Ai[s] = bih1[(size_t)nm*4*KNN + s];
    }
    #pragma unroll
    for (int q2i=1;q2i<4;++q2i){
      float T[KNN]; int Ti[KNN];
      #pragma unroll
      for (int s=0;s<KNN;++s){
        T[s]  = bdh1[((size_t)nm*4+q2i)*KNN + s];
        Ti[s] = bih1[((size_t)nm*4+q2i)*KNN + s];
      }
      float O[KNN]; int Oi[KNN];
      #pragma unroll
      for (int s=0;s<KNN;++s){
        bool ta = A[0] <= T[0];
        O[s]  = ta ? A[0]  : T[0];
        Oi[s] = ta ? Ai[0] : Ti[0];
        #pragma unroll
        for (int u=0;u<KNN-1;++u){
          A[u]  = ta ? A[u+1]  : A[u];
          Ai[u] = ta ? Ai[u+1] : Ai[u];
          T[u]  = ta ? T[u]    : T[u+1];
          Ti[u] = ta ? Ti[u]   : Ti[u+1];
        }
      }
      #pragma unroll
      for (int s=0;s<KNN;++s){ A[s]=O[s]; Ai[s]=Oi[s]; }
    }
    #pragma unroll
    for (int s=0;s<KNN;++s) sidx[t*KNN+s] = Ai[s];
  }
  __syncthreads();

  int wv = __builtin_amdgcn_readfirstlane(t >> 6);  // wave id = octile (forced uniform)
  int p  = t & 63;           // local point 0..63 (one per lane)
  int cb = wv*8;
  int n  = b*NP + g*64 + p;
  float* h0row = &hx0[p*65];
  float* h1row = &hx1[p*65];
  const float* wbq = w1b + cb;   // wave-uniform base -> s_load path
  const float* wcq = w1c + cb;

  float sbb[8], sbc[8];          // uniform -> SGPRs
  #pragma unroll
  for (int o=0;o<8;++o){ sbb[o]=b1b[cb+o]; sbc[o]=b1c[cb+o]; }

  float par[8];
  {
    float4 v0 = *(const float4*)&pa[(size_t)n*64 + cb];
    float4 v1 = *(const float4*)&pa[(size_t)n*64 + cb + 4];
    par[0]=v0.x; par[1]=v0.y; par[2]=v0.z; par[3]=v0.w;
    par[4]=v1.x; par[5]=v1.y; par[6]=v1.z; par[7]=v1.w;
  }
  float acc[8];
  #pragma unroll
  for (int o=0;o<8;++o) acc[o]=0.0f;

  #pragma unroll 1
  for (int kp=0; kp<5; ++kp){
    int j0 = sidx[p*KNN + kp*2];
    int j1 = sidx[p*KNN + kp*2 + 1];
    float4 u00 = *(const float4*)&pb[((size_t)b*NP + j0)*64 + cb];
    float4 u01 = *(const float4*)&pb[((size_t)b*NP + j0)*64 + cb + 4];
    float4 u10 = *(const float4*)&pb[((size_t)b*NP + j1)*64 + cb];
    float4 u11 = *(const float4*)&pb[((size_t)b*NP + j1)*64 + cb + 4];

    // ---- layer a (factored): h1 = lrelu(pa_i + pb_j)
    h0row[cb+0]=lrelu(par[0]+u00.x); h0row[cb+1]=lrelu(par[1]+u00.y);
    h0row[cb+2]=lrelu(par[2]+u00.z); h0row[cb+3]=lrelu(par[3]+u00.w);
    h0row[cb+4]=lrelu(par[4]+u01.x); h0row[cb+5]=lrelu(par[5]+u01.y);
    h0row[cb+6]=lrelu(par[6]+u01.z); h0row[cb+7]=lrelu(par[7]+u01.w);
    h1row[cb+0]=lrelu(par[0]+u10.x); h1row[cb+1]=lrelu(par[1]+u10.y);
    h1row[cb+2]=lrelu(par[2]+u10.z); h1row[cb+3]=lrelu(par[3]+u10.w);
    h1row[cb+4]=lrelu(par[4]+u11.x); h1row[cb+5]=lrelu(par[5]+u11.y);
    h1row[cb+6]=lrelu(par[6]+u11.z); h1row[cb+7]=lrelu(par[7]+u11.w);
    __syncthreads();

    // ---- layer b: h from LDS (2-way aliased b32), weights scalar from global
    float pr0[8], pr1[8];
    #pragma unroll
    for (int o=0;o<8;++o){ pr0[o]=sbb[o]; pr1[o]=sbb[o]; }
    #pragma unroll 4
    for (int c=0;c<64;++c){
      float hv0 = h0row[c];
      float hv1 = h1row[c];
      float4 w0 = *(const float4*)&wbq[c*64];
      float4 w1 = *(const float4*)&wbq[c*64+4];
      pr0[0]=fmaf(hv0,w0.x,pr0[0]); pr0[1]=fmaf(hv0,w0.y,pr0[1]);
      pr0[2]=fmaf(hv0,w0.z,pr0[2]); pr0[3]=fmaf(hv0,w0.w,pr0[3]);
      pr0[4]=fmaf(hv0,w1.x,pr0[4]); pr0[5]=fmaf(hv0,w1.y,pr0[5]);
      pr0[6]=fmaf(hv0,w1.z,pr0[6]); pr0[7]=fmaf(hv0,w1.w,pr0[7]);
      pr1[0]=fmaf(hv1,w0.x,pr1[0]); pr1[1]=fmaf(hv1,w0.y,pr1[1]);
      pr1[2]=fmaf(hv1,w0.z,pr1[2]); pr1[3]=fmaf(hv1,w0.w,pr1[3]);
      pr1[4]=fmaf(hv1,w1.x,pr1[4]); pr1[5]=fmaf(hv1,w1.y,pr1[5]);
      pr1[6]=fmaf(hv1,w1.z,pr1[6]); pr1[7]=fmaf(hv1,w1.w,pr1[7]);
    }
    __syncthreads();              // all h reads done before overwrite
    #pragma unroll
    for (int o=0;o<8;++o){ h0row[cb+o]=lrelu(pr0[o]); h1row[cb+o]=lrelu(pr1[o]); }
    __syncthreads();

    // ---- layer c: accumulate my 8 outputs, both edges
    #pragma unroll
    for (int o=0;o<8;++o){ pr0[o]=sbc[o]; pr1[o]=sbc[o]; }
    #pragma unroll 4
    for (int c=0;c<64;++c){
      float hv0 = h0row[c];
      float hv1 = h1row[c];
      float4 w0 = *(const float4*)&wcq[c*64];
      float4 w1 = *(const float4*)&wcq[c*64+4];
      pr0[0]=fmaf(hv0,w0.x,pr0[0]); pr0[1]=fmaf(hv0,w0.y,pr0[1]);
      pr0[2]=fmaf(hv0,w0.z,pr0[2]); pr0[3]=fmaf(hv0,w0.w,pr0[3]);
      pr0[4]=fmaf(hv0,w1.x,pr0[4]); pr0[5]=fmaf(hv0,w1.y,pr0[5]);
      pr0[6]=fmaf(hv0,w1.z,pr0[6]); pr0[7]=fmaf(hv0,w1.w,pr0[7]);
      pr1[0]=fmaf(hv1,w0.x,pr1[0]); pr1[1]=fmaf(hv1,w0.y,pr1[1]);
      pr1[2]=fmaf(hv1,w0.z,pr1[2]); pr1[3]=fmaf(hv1,w0.w,pr1[3]);
      pr1[4]=fmaf(hv1,w1.x,pr1[4]); pr1[5]=fmaf(hv1,w1.y,pr1[5]);
      pr1[6]=fmaf(hv1,w1.z,pr1[6]); pr1[7]=fmaf(hv1,w1.w,pr1[7]);
    }
    #pragma unroll
    for (int o=0;o<8;++o) acc[o] += lrelu(pr0[o]) + lrelu(pr1[o]);
    __syncthreads();              // rows free for next pair
  }

  // ---- epilogue: per-thread squares, stage acc into hx0
  {
    float s = 0.0f;
    #pragma unroll
    for (int o=0;o<8;++o) s = fmaf(acc[o], acc[o], s);
    ssq8[p*8 + wv] = s;
  }
  #pragma unroll
  for (int o=0;o<8;++o) h0row[cb+o] = acc[o];
  __syncthreads();

  // coalesced x1 write from staged hx0
  for (int i=t; i<1024; i+=512){
    int p2 = i >> 4;
    int c4 = (i & 15) << 2;
    float4 v;
    v.x = hx0[p2*65 + c4];
    v.y = hx0[p2*65 + c4 + 1];
    v.z = hx0[p2*65 + c4 + 2];
    v.w = hx0[p2*65 + c4 + 3];
    *(float4*)&x1[((size_t)(b*NP + g*64 + p2))*64 + c4] = v;
  }

  // fused x1-mean partial + sq2
  if (t < 64){
    float s2 = 0.0f;
    #pragma unroll 8
    for (int p2=0;p2<64;++p2) s2 += hx0[p2*65 + t];
    atomicAdd(&fmean[b*192 + t], s2);
    float ss = 0.0f;
    #pragma unroll
    for (int w=0;w<8;++w) ss += ssq8[t*8 + w];
    sq2[b*NP + g*64 + t] = ss;
  }
}

// ---------------- knn2 phase A: top-10 per (i-point, j-quarter of [0,256)) ----------------
// Grid 1024 -> 4 blocks/CU, 16 waves/CU (R10-proven). Exact per-quarter lists; merge in
// knn2_mergeT reproduces the identical seed list + threshold.
__global__ __launch_bounds__(256,4) void knn2_thresh_q(const float* __restrict__ x1,
    const float* __restrict__ sq2,
    float* __restrict__ bdh2, int* __restrict__ bih2){
  __shared__ alignas(16) float sj[64*64];    // 16 KB: 64 j-rows
  __shared__ float ssq[64];
  int bid = blockIdx.x;        // 1024 = 64 b x 4 ig x 4 jq
  int b  = bid >> 4;
  int ig = (bid >> 2) & 3;
  int jq = bid & 3;
  int t = threadIdx.x;
  {
    const float4* src = (const float4*)(x1 + ((size_t)b*NP + jq*64)*64);
    for (int u=t; u<1024; u+=256) ((float4*)sj)[u] = src[u];
    if (t < 64) ssq[t] = sq2[b*NP + jq*64 + t];
  }
  int n = b*NP + ig*256 + t;
  float xi[64];
  #pragma unroll
  for (int c=0;c<64;c+=4){
    float4 v = *(const float4*)&x1[(size_t)n*64+c];
    xi[c]=v.x; xi[c+1]=v.y; xi[c+2]=v.z; xi[c+3]=v.w;
  }
  float sqi = sq2[n];
  float bd[KNN]; int bi[KNN];
  #pragma unroll
  for (int s=0;s<KNN;++s){ bd[s]=FLT_MAX; bi[s]=0; }
  __syncthreads();
  #pragma unroll 2
  for (int j=0;j<64;++j){
    float d0=0.f, d1=0.f, d2a=0.f, d3=0.f;   // 4-way chain split
    #pragma unroll
    for (int c=0;c<64;c+=16){
      float4 v0 = *(const float4*)&sj[j*64+c];
      float4 v1 = *(const float4*)&sj[j*64+c+4];
      float4 v2 = *(const float4*)&sj[j*64+c+8];
      float4 v3 = *(const float4*)&sj[j*64+c+12];
      d0=fmaf(xi[c+0],v0.x,d0);  d0=fmaf(xi[c+1],v0.y,d0);
      d0=fmaf(xi[c+2],v0.z,d0);  d0=fmaf(xi[c+3],v0.w,d0);
      d1=fmaf(xi[c+4],v1.x,d1);  d1=fmaf(xi[c+5],v1.y,d1);
      d1=fmaf(xi[c+6],v1.z,d1);  d1=fmaf(xi[c+7],v1.w,d1);
      d2a=fmaf(xi[c+8],v2.x,d2a);  d2a=fmaf(xi[c+9],v2.y,d2a);
      d2a=fmaf(xi[c+10],v2.z,d2a); d2a=fmaf(xi[c+11],v2.w,d2a);
      d3=fmaf(xi[c+12],v3.x,d3);  d3=fmaf(xi[c+13],v3.y,d3);
      d3=fmaf(xi[c+14],v3.z,d3);  d3=fmaf(xi[c+15],v3.w,d3);
    }
    float dot = (d0+d1)+(d2a+d3);
    float d2 = (sqi + ssq[j]) - 2.0f*dot;
    if (d2 < bd[KNN-1]){
      TOP10_INSERT(d2, jq*64+j, bd, bi);
    }
  }
  #pragma unroll
  for (int s=0;s<KNN;++s){
    bdh2[((size_t)n*4 + jq)*KNN + s] = bd[s];
    bih2[((size_t)n*4 + jq)*KNN + s] = bi[s];
  }
}

// ---------------- knn2 mergeT: fuse 4 quarter-lists -> seed list + threshold ----------------
__global__ __launch_bounds__(256) void knn2_mergeT(const float* __restrict__ bdh2,
    const int* __restrict__ bih2,
    float* __restrict__ seed_d, int* __restrict__ seed_i, float* __restrict__ Tout){
  int nm = blockIdx.x*256 + threadIdx.x;
  float A[KNN]; int Ai[KNN];
  #pragma unroll
  for (int s=0;s<KNN;++s){
    A[s]  = bdh2[(size_t)nm*4*KNN + s];
    Ai[s] = bih2[(size_t)nm*4*KNN + s];
  }
  #pragma unroll
  for (int q2i=1;q2i<4;++q2i){
    float T[KNN]; int Ti[KNN];
    #pragma unroll
    for (int s=0;s<KNN;++s){
      T[s]  = bdh2[((size_t)nm*4+q2i)*KNN + s];
      Ti[s] = bih2[((size_t)nm*4+q2i)*KNN + s];
    }
    float O[KNN]; int Oi[KNN];
    #pragma unroll
    for (int s=0;s<KNN;++s){
      bool ta = A[0] <= T[0];
      O[s]  = ta ? A[0]  : T[0];
      Oi[s] = ta ? Ai[0] : Ti[0];
      #pragma unroll
      for (int u=0;u<KNN-1;++u){
        A[u]  = ta ? A[u+1]  : A[u];
        Ai[u] = ta ? Ai[u+1] : Ai[u];
        T[u]  = ta ? T[u]    : T[u+1];
        Ti[u] = ta ? Ti[u]   : Ti[u+1];
      }
    }
    #pragma unroll
    for (int s=0;s<KNN;++s){ A[s]=O[s]; Ai[s]=Oi[s]; }
  }
  #pragma unroll
  for (int s=0;s<KNN;++s){
    seed_d[(size_t)nm*KNN + s] = A[s];
    seed_i[(size_t)nm*KNN + s] = Ai[s];
  }
  Tout[nm] = A[KNN-1];
}

// ---------------- knn2 phase B: filtered scan of j in [256,1024), 4 chunks ----------------
// (R11-proven form: 2 tiles x 96 rows, launch_bounds(256,2), unroll 2. The R12 3x64
// restructure regressed: grid already gave 4 blocks/CU; extra barriers were pure cost.)
__global__ __launch_bounds__(256,2) void knn2_scan(const float* __restrict__ x1,
    const float* __restrict__ sq2, const float* __restrict__ Tin,
    float2* __restrict__ surv, int* __restrict__ cnt4){
  __shared__ alignas(16) float sj[96*64];    // 24 KB
  __shared__ float ssq[96];
  int bid = blockIdx.x;     // 1024 = 64 b x 4 ig x 4 jc
  int b  = bid >> 4;
  int ig = (bid >> 2) & 3;
  int jc = bid & 3;
  int t = threadIdx.x;
  int n = b*NP + ig*256 + t;
  float xi[64];
  #pragma unroll
  for (int c=0;c<64;c+=4){
    float4 v = *(const float4*)&x1[(size_t)n*64+c];
    xi[c]=v.x; xi[c+1]=v.y; xi[c+2]=v.z; xi[c+3]=v.w;
  }
  float sqi = sq2[n];
  float thr = Tin[n];
  int cnt = 0;
  float2* mybuf = surv + ((size_t)n*4 + jc)*SCAP;
  int jbase0 = 256 + jc*192;
  for (int tile=0; tile<2; ++tile){
    int jb = jbase0 + tile*96;
    __syncthreads();
    const float4* src = (const float4*)(x1 + ((size_t)b*NP + jb)*64);
    for (int u=t; u<1536; u+=256) ((float4*)sj)[u] = src[u];
    if (t < 96) ssq[t] = sq2[b*NP + jb + t];
    __syncthreads();
    #pragma unroll 2
    for (int j=0;j<96;++j){
      float a0=0.f, a1=0.f;                  // 2-way chain split
      #pragma unroll
      for (int c=0;c<64;c+=8){
        float4 v0 = *(const float4*)&sj[j*64+c];
        float4 v1 = *(const float4*)&sj[j*64+c+4];
        a0=fmaf(xi[c+0],v0.x,a0); a0=fmaf(xi[c+1],v0.y,a0);
        a0=fmaf(xi[c+2],v0.z,a0); a0=fmaf(xi[c+3],v0.w,a0);
        a1=fmaf(xi[c+4],v1.x,a1); a1=fmaf(xi[c+5],v1.y,a1);
        a1=fmaf(xi[c+6],v1.z,a1); a1=fmaf(xi[c+7],v1.w,a1);
      }
      float d2 = (sqi + ssq[j]) - 2.0f*(a0+a1);
      if (d2 <= thr && cnt < SCAP){
        float2 e; e.x = d2; e.y = __int_as_float(jb + j);
        mybuf[cnt] = e;
        cnt++;
      }
    }
  }
  cnt4[(size_t)n*4 + jc] = cnt;
}

// ---------------- knn2 phase C: replay survivors into seed list ----------------
__global__ void knn2_select(const float* __restrict__ seed_d, const int* __restrict__ seed_i,
    const float2* __restrict__ surv, const int* __restrict__ cnt4,
    int* __restrict__ idx2){
  int n = blockIdx.x*256 + threadIdx.x;
  float bd[KNN]; int bi[KNN];
  #pragma unroll
  for (int s=0;s<KNN;++s){
    bd[s] = seed_d[(size_t)n*KNN + s];
    bi[s] = seed_i[(size_t)n*KNN + s];
  }
  #pragma unroll 1
  for (int c=0;c<4;++c){
    int nc = cnt4[(size_t)n*4 + c];
    const float2* buf = surv + ((size_t)n*4 + c)*SCAP;
    #pragma unroll 1
    for (int k=0;k<nc;++k){
      float2 e = buf[k];
      float d = e.x; int j = __float_as_int(e.y);
      if (d < bd[KNN-1]){
        TOP10_INSERT(d, j, bd, bi);
      }
    }
  }
  #pragma unroll
  for (int s=0;s<KNN;++s) idx2[(size_t)n*KNN+s] = bi[s];
}

// ---------------- q/r GEMM for edgeconv2: q=x1*Wbot, r=x1*(Wtop-Wbot)+b ----------------
// 4-way op-split: grid 1024, 4 blocks/CU, 16 waves/CU. (R5 proven form.)
__global__ __launch_bounds__(256) void qr2_kernel(const float* __restrict__ x1,
    const float* __restrict__ wcombg, const float* __restrict__ b2,
    float* __restrict__ q2, float* __restrict__ r2){
  __shared__ alignas(16) float sw[4096];     // 16 KB: rows 0..31 = a(oq+r), 32..63 = c(128+oq+r)
  __shared__ float sb2l[32];
  int t = threadIdx.x;
  int oq = (blockIdx.x & 3) * 32;
  int n  = (blockIdx.x >> 2) * 256 + t;
  for (int u=t; u<1024; u+=256){
    int row = u >> 4;
    int c4  = u & 15;
    int src = (row < 32) ? (oq + row) : (96 + oq + row);
    ((float4*)sw)[u] = ((const float4*)wcombg)[src*16 + c4];
  }
  if (t < 32) sb2l[t] = b2[oq + t];
  __syncthreads();
  float xi[64];
  #pragma unroll
  for (int c=0;c<64;c+=4){
    float4 v = *(const float4*)&x1[(size_t)n*64+c];
    xi[c]=v.x; xi[c+1]=v.y; xi[c+2]=v.z; xi[c+3]=v.w;
  }
  #pragma unroll 1
  for (int op=0; op<32; op+=4){
    float q0=0,q1=0,q2a=0,q3=0, r0,r1,r2a,r3;
    r0=sb2l[op]; r1=sb2l[op+1]; r2a=sb2l[op+2]; r3=sb2l[op+3];
    #pragma unroll
    for (int c=0;c<64;c+=4){
      float4 a0 = *(const float4*)&sw[(op+0)*64+c];
      float4 a1 = *(const float4*)&sw[(op+1)*64+c];
      float4 a2 = *(const float4*)&sw[(op+2)*64+c];
      float4 a3 = *(const float4*)&sw[(op+3)*64+c];
      float4 c0 = *(const float4*)&sw[(32+op+0)*64+c];
      float4 c1 = *(const float4*)&sw[(32+op+1)*64+c];
      float4 c2 = *(const float4*)&sw[(32+op+2)*64+c];
      float4 c3 = *(const float4*)&sw[(32+op+3)*64+c];
      q0=fmaf(xi[c],a0.x,q0); q0=fmaf(xi[c+1],a0.y,q0); q0=fmaf(xi[c+2],a0.z,q0); q0=fmaf(xi[c+3],a0.w,q0);
      q1=fmaf(xi[c],a1.x,q1); q1=fmaf(xi[c+1],a1.y,q1); q1=fmaf(xi[c+2],a1.z,q1); q1=fmaf(xi[c+3],a1.w,q1);
      q2a=fmaf(xi[c],a2.x,q2a); q2a=fmaf(xi[c+1],a2.y,q2a); q2a=fmaf(xi[c+2],a2.z,q2a); q2a=fmaf(xi[c+3],a2.w,q2a);
      q3=fmaf(xi[c],a3.x,q3); q3=fmaf(xi[c+1],a3.y,q3); q3=fmaf(xi[c+2],a3.z,q3); q3=fmaf(xi[c+3],a3.w,q3);
      r0=fmaf(xi[c],c0.x,r0); r0=fmaf(xi[c+1],c0.y,r0); r0=fmaf(xi[c+2],c0.z,r0); r0=fmaf(xi[c+3],c0.w,r0);
      r1=fmaf(xi[c],c1.x,r1); r1=fmaf(xi[c+1],c1.y,r1); r1=fmaf(xi[c+2],c1.z,r1); r1=fmaf(xi[c+3],c1.w,r1);
      r2a=fmaf(xi[c],c2.x,r2a); r2a=fmaf(xi[c+1],c2.y,r2a); r2a=fmaf(xi[c+2],c2.z,r2a); r2a=fmaf(xi[c+3],c2.w,r2a);
      r3=fmaf(xi[c],c3.x,r3); r3=fmaf(xi[c+1],c3.y,r3); r3=fmaf(xi[c+2],c3.z,r3); r3=fmaf(xi[c+3],c3.w,r3);
    }
    float4 qv; qv.x=q0; qv.y=q1; qv.z=q2a; qv.w=q3;
    float4 rv; rv.x=r0; rv.y=r1; rv.z=r2a; rv.w=r3;
    *(float4*)&q2[(size_t)n*128+oq+op] = qv;
    *(float4*)&r2[(size_t)n*128+oq+op] = rv;
  }
}

// ---------------- edgeconv2 gather + fused mean (never materialize x2) ----------------
// k-loop fully unrolled: 10 idx2 loads issued first, then 10 independent q2 row loads
// (MLP ~10 in flight vs 1 with the serialized loop); accumulation stays in k order.
__global__ __launch_bounds__(256,4) void ec2_gather_kernel(
    const float* __restrict__ q2, const float* __restrict__ r2,
    const int* __restrict__ idx2, float* __restrict__ fmean){
  __shared__ alignas(16) float4 red[256];
  int t = threadIdx.x;
  int b = blockIdx.x >> 7, blk = blockIdx.x & 127;
  int p = t >> 5, c4 = t & 31;
  int n = b*NP + blk*8 + p;
  float4 r = *(const float4*)&r2[(size_t)n*128 + c4*4];
  int jA[KNN];
  #pragma unroll
  for (int k=0;k<KNN;++k) jA[k] = idx2[n*KNN+k];
  float4 qv[KNN];
  #pragma unroll
  for (int k=0;k<KNN;++k)
    qv[k] = *(const float4*)&q2[((size_t)b*NP + jA[k])*128 + c4*4];
  float4 acc; acc.x=0; acc.y=0; acc.z=0; acc.w=0;
  #pragma unroll
  for (int k=0;k<KNN;++k){
    acc.x += lrelu(r.x+qv[k].x);
    acc.y += lrelu(r.y+qv[k].y);
    acc.z += lrelu(r.z+qv[k].z);
    acc.w += lrelu(r.w+qv[k].w);
  }
  red[t] = acc;
  __syncthreads();
  if (t < 128){ float4 o = red[t+128]; red[t].x+=o.x; red[t].y+=o.y; red[t].z+=o.z; red[t].w+=o.w; }
  __syncthreads();
  if (t < 64){ float4 o = red[t+64]; red[t].x+=o.x; red[t].y+=o.y; red[t].z+=o.z; red[t].w+=o.w; }
  __syncthreads();
  if (t < 32){
    float4 s = red[t]; float4 o = red[t+32];
    s.x+=o.x; s.y+=o.y; s.z+=o.z; s.w+=o.w;
    float* dst = &fmean[b*192 + 64 + c4*4];
    atomicAdd(dst+0, s.x); atomicAdd(dst+1, s.y);
    atomicAdd(dst+2, s.z); atomicAdd(dst+3, s.w);
  }
}

// ---------------- head, split for parallelism ----------------
__global__ __launch_bounds__(256) void headA_kernel(const float* __restrict__ fmean,
    const float* __restrict__ wl, const float* __restrict__ bl,
    float* __restrict__ o1g){
  __shared__ float v0[192];
  int b = blockIdx.x >> 2, ch = blockIdx.x & 3, t = threadIdx.x;
  if (t < 192) v0[t] = fmean[b*192 + t] * (1.0f/1024.0f);
  __syncthreads();
  int o = ch*256 + t;
  float s = bl[o];
  #pragma unroll 8
  for (int c=0;c<192;++c) s = fmaf(v0[c], wl[c*1024 + o], s);
  o1g[b*1024 + o] = s;
}

__global__ __launch_bounds__(256) void headB_kernel(const float* __restrict__ o1g,
    const float* __restrict__ wm1, const float* __restrict__ bm1,
    float* __restrict__ h1g){
  __shared__ alignas(16) float vo[1024];
  int b = blockIdx.x >> 1, ch = blockIdx.x & 1, t = threadIdx.x;
  ((float4*)vo)[t] = ((const float4*)(o1g + b*1024))[t];
  __syncthreads();
  int o = ch*256 + t;
  float s = bm1[o];
  #pragma unroll 8
  for (int c=0;c<1024;++c) s = fmaf(vo[c], wm1[c*512 + o], s);
  h1g[b*512 + o] = lrelu(s);
}

__global__ __launch_bounds__(256) void headC_kernel(const float* __restrict__ h1g,
    const float* __restrict__ wm2, const float* __restrict__ bm2,
    const float* __restrict__ wm3, const float* __restrict__ bm3,
    float* __restrict__ out){
  __shared__ alignas(16) float vh[512];
  __shared__ float h2[256];
  int b = blockIdx.x, t = threadIdx.x;
  ((float2*)vh)[t] = ((const float2*)(h1g + b*512))[t];
  __syncthreads();
  float s = bm2[t];
  #pragma unroll 8
  for (int c=0;c<512;++c) s = fmaf(vh[c], wm2[c*256 + t], s);
  h2[t] = lrelu(s);
  __syncthreads();
  if (t < 3){
    float s2 = bm3[t];
    #pragma unroll 8
    for (int c=0;c<256;++c) s2 = fmaf(h2[c], wm3[c*3 + t], s2);
    out[b*3 + t] = s2;
  }
}

extern "C" void kernel_launch(void* const* d_in, const int* in_sizes, int n_in,
                              void* d_out, int out_size, void* d_ws, size_t ws_size,
                              hipStream_t stream) {
  const float* x   = (const float*)d_in[0];
  const float* pos = (const float*)d_in[1];
  const float* w1a = (const float*)d_in[3];
  const float* b1a = (const float*)d_in[4];
  const float* w1b = (const float*)d_in[5];
  const float* b1b = (const float*)d_in[6];
  const float* w1c = (const float*)d_in[7];
  const float* b1c = (const float*)d_in[8];
  const float* w2  = (const float*)d_in[9];
  const float* b2  = (const float*)d_in[10];
  const float* wl  = (const float*)d_in[11];
  const float* bl  = (const float*)d_in[12];
  const float* wm1 = (const float*)d_in[13];
  const float* bm1 = (const float*)d_in[14];
  const float* wm2 = (const float*)d_in[15];
  const float* bm2 = (const float*)d_in[16];
  const float* wm3 = (const float*)d_in[17];
  const float* bm3 = (const float*)d_in[18];
  float* out = (float*)d_out;

  float* ws_f  = (float*)d_ws;
  float* xx    = ws_f;                    // 262144 f
  float* x1    = xx + 262144;             // 4194304 f (16 MB)
  float* sq2   = x1 + 4194304;            // 65536 f
  int*   idx2  = (int*)(sq2 + 65536);     // 655360 i
  float* q2    = (float*)(idx2 + 655360); // 8388608 f (32 MB)
  float* r2    = q2 + 8388608;            // 8388608 f (32 MB)
  float* wcomb = r2 + 8388608;            // 16384 f
  float* fmean = wcomb + 16384;           // 12288 f
  float* o1g   = fmean + 12288;           // 65536 f
  float* h1g   = o1g + 65536;             // 32768 f
  float* seedd = h1g + 32768;             // 655360 f
  int*   seedi = (int*)(seedd + 655360);  // 655360 i
  float* Tbuf  = (float*)(seedi + 655360);// 65536 f
  int*   cnt4  = (int*)(Tbuf + 65536);    // 262144 i
  // Temporal overlays:
  // r2 region: knn1 writes bdh1/bih1 -> ec1 merge reads -> knn2_thresh_q REUSES the
  //   region for bdh2/bih2 -> knn2_mergeT reads -> qr2 overwrites r2 (strictly later).
  float* bdh1  = r2;                      // 2621440 f
  int*   bih1  = (int*)(r2 + 2621440);    // 2621440 i
  float* bdh2  = bdh1;
  int*   bih2  = bih1;
  // q2 region: prep writes pa/pb -> ec1 consumes -> surv (scan) -> qr2 overwrites q2.
  float2* surv = (float2*)q2;             // knn2 survivors (written after ec1)
  float* pa    = q2;                      // 4194304 f (16 MB)
  float* pb    = q2 + 4194304;            // 4194304 f (16 MB)

  prep_fused<<<4464, 256, 0, stream>>>(x, pos, w2, w1a, b1a, xx, wcomb, fmean, pa, pb);
  knn1_kernel<<<1024, 256, 0, stream>>>(xx, bdh1, bih1);
  edgeconv1_kernel<<<1024, 512, 0, stream>>>(pa, pb, bdh1, bih1, w1b, b1b, w1c, b1c, x1, sq2, fmean);
  knn2_thresh_q<<<1024, 256, 0, stream>>>(x1, sq2, bdh2, bih2);
  knn2_mergeT<<<256, 256, 0, stream>>>(bdh2, bih2, seedd, seedi, Tbuf);
  knn2_scan<<<1024, 256, 0, stream>>>(x1, sq2, Tbuf, surv, cnt4);
  knn2_select<<<256, 256, 0, stream>>>(seedd, seedi, surv, cnt4, idx2);
  qr2_kernel<<<1024, 256, 0, stream>>>(x1, wcomb, b2, q2, r2);
  ec2_gather_kernel<<<8192, 256, 0, stream>>>(q2, r2, idx2, fmean);
  headA_kernel<<<256, 256, 0, stream>>>(fmean, wl, bl, o1g);
  headB_kernel<<<128, 256, 0, stream>>>(o1g, wm1, bm1, h1g);
  headC_kernel<<<64, 256, 0, stream>>>(h1g, wm2, bm2, wm3, bm3, out);
}